// Round 11
// baseline (202.969 us; speedup 1.0000x reference)
//
#include <hip/hip_runtime.h>

// Gather + ragged segment XOR reduction.
// History:
//  R1/R2: direct gather 142 us — L2-miss line-fill bound (table >> 4 MB/XCD L2).
//  R4: slice-bucket + XCD-pinned gather; gather ~60, bucket 67 (occupancy).
//  R5: global-atomic bucketizer regressed (139 MB scattered writes). Reverted.
//  R6: LDS-staged ordered scatter + binary-search labels: bucket ~30, gather
//    61.4, total 189 us.
//  R7: padded 32B rows: gather flat BUT slice pair hit 4 MB = L2 capacity
//    (FETCH 28->75 MB) — confounded test. Reverted.
//  R8: ballot-aggregated bucket atomics: 30->96 us (VALU-bound). Reverted.
//  R9: u64 LDS atomicXor: WRITE 20->100 MB, gather 110 us — u64 LDS atomics
//    take a memory-backed path on gfx950. NEVER use. Reverted.
//  R10: 2x unrolled gather: neutral (61.1). Total 188.4 (best).
//  R11: R10 + parity-aligned 3-transaction row load (x2+x2+x1 / x1+x2+x2),
//    raw 20 B table (slice pair stays 2.6 MB — no thrash). Clean test of the
//    TA-transaction-rate theory (~1 trans/cyc/CU).

#define HPG        128     // hints per group
#define NSL        16      // slices (idx>>16), N <= 2^20
#define STAGE_CAP  12288   // tokens staged in LDS; mean 8192, +10 sigma

__device__ __forceinline__ int clip_idx(int v, int N) {
    return min(max(v, 0), N - 1);
}

// Parity-aligned 20-byte row load: 3 transactions (dwords at d0..d0+4).
// d0 = idx*5; d0 even  -> x2@d0, x2@d0+2, x1@d0+4
//             d0 odd   -> x1@d0, x2@d0+1, x2@d0+3
__device__ __forceinline__ void load_row5(const int* __restrict__ e, int idx,
                                          int& e0, int& e1, int& e2, int& e3,
                                          int& e4) {
    const int d0 = idx * 5;
    const bool even = (d0 & 1) == 0;
    const int pb = (d0 + 1) >> 1;          // even: d0/2, odd: (d0+1)/2
    const int2 u = ((const int2*)e)[pb];
    const int2 v = ((const int2*)e)[pb + 1];
    const int  w = e[even ? d0 + 4 : d0];
    e0 = even ? u.x : w;
    e1 = even ? u.y : u.x;
    e2 = even ? v.x : u.y;
    e3 = even ? v.y : v.x;
    e4 = even ? w   : v.y;
}

// ---------------- Kernel A: bucketize (one group per block) — R6 form ----------------
__global__ __launch_bounds__(1024) void bucket_kernel(
    const int* __restrict__ blocks,
    const int* __restrict__ offsets,
    const int* __restrict__ starts,
    const int* __restrict__ bs_ptr,
    const int* __restrict__ entries,     // overflow path only
    int* __restrict__ out,               // overflow path only
    unsigned int* __restrict__ buck,     // [T] u32: idx(20) | localHint(<<20)
    unsigned int* __restrict__ tab,      // [NG*NSL*2] {absBase, count}
    int H, int N, int T)
{
    __shared__ unsigned int stage[STAGE_CAP];
    __shared__ int lstart[HPG + 1];
    __shared__ unsigned int cnt[NSL], off[NSL], lcur[NSL];

    const int g  = blockIdx.x;
    const int t  = threadIdx.x;
    const int h0 = g * HPG;
    const int h1 = min(H, h0 + HPG);
    const int nh = h1 - h0;
    const int bs = bs_ptr[0];

    if (t < nh) lstart[t] = starts[h0 + t];
    if (t == 0) lstart[nh] = (h1 < H) ? starts[h1] : T;
    if (t < NSL) { cnt[t] = 0; lcur[t] = 0; }
    __syncthreads();

    const int tokBase = lstart[0];
    const int count   = lstart[nh] - tokBase;
    const int staged  = min(count, STAGE_CAP);

    // pass 1: idx + hint (binary search) -> LDS stage; per-slice histogram
    for (int i = t; i < staged; i += 1024) {
        const int gpos = tokBase + i;
        const int idx  = clip_idx(blocks[gpos] * bs + offsets[gpos], N);
        int lo = 0, hi = nh - 1;                 // largest h: lstart[h] <= gpos
        while (lo < hi) {
            int m = (lo + hi + 1) >> 1;
            if (lstart[m] <= gpos) lo = m; else hi = m - 1;
        }
        stage[i] = (unsigned int)idx | ((unsigned int)lo << 20);
        atomicAdd(&cnt[(unsigned int)idx >> 16], 1u);
    }
    __syncthreads();

    // exclusive prefix over 16 slice counts
    if (t == 0) {
        unsigned int run = 0;
        for (int s = 0; s < NSL; ++s) { off[s] = run; run += cnt[s]; }
    }
    __syncthreads();

    if (t < NSL) {
        tab[(g * NSL + t) * 2 + 0] = (unsigned int)tokBase + off[t];
        tab[(g * NSL + t) * 2 + 1] = cnt[t];
    }

    // pass 2: ordered scatter into the group's own CSR range
    for (int i = t; i < staged; i += 1024) {
        const unsigned int w = stage[i];
        const unsigned int s = (w >> 16) & (NSL - 1);
        const unsigned int r = atomicAdd(&lcur[s], 1u);
        buck[(unsigned int)tokBase + off[s] + r] = w;
    }

    // overflow remainder (count > STAGE_CAP): statistically never; correctness.
    for (int i = staged + t; i < count; i += 1024) {
        const int gpos = tokBase + i;
        const int idx  = clip_idx(blocks[gpos] * bs + offsets[gpos], N);
        int lo = 0, hi = nh - 1;
        while (lo < hi) {
            int m = (lo + hi + 1) >> 1;
            if (lstart[m] <= gpos) lo = m; else hi = m - 1;
        }
        const int* row = entries + (long)idx * 5;
        int* o5 = out + (long)(h0 + lo) * 5;
        atomicXor(&o5[0], row[0]); atomicXor(&o5[1], row[1]);
        atomicXor(&o5[2], row[2]); atomicXor(&o5[3], row[3]);
        atomicXor(&o5[4], row[4]);
    }
}

// ---------------- Kernel B: XCD-pinned gather + LDS accumulate ----------------
// Grid = 2048 (resident capacity) so blockIdx&7 -> XCD round-robin holds.
// Block (x,g) touches only slices {x, x+8} -> 2.62 MB entries, L2-resident.
// R11: parity-aligned 3-transaction row loads; 2x unrolled; 5x u32 LDS atomics.
__global__ __launch_bounds__(256) void gather_kernel(
    const unsigned int* __restrict__ buck,
    const unsigned int* __restrict__ tab,
    const int* __restrict__ entries,
    int* __restrict__ out,
    int H, int NG, int nSl, int groupsPerBlock)
{
    __shared__ int acc[HPG * 5];

    const int B = blockIdx.x;
    const int x = B & 7;
    const int g0 = B >> 3;
    const int t = threadIdx.x;
    const int gStride = gridDim.x >> 3;

    for (int k = 0; k < groupsPerBlock; ++k) {
        const int g = g0 + k * gStride;
        if (g >= NG) break;

        for (int i = t; i < HPG * 5; i += 256) acc[i] = 0;
        __syncthreads();

        for (int s = x; s < nSl; s += 8) {
            const unsigned int base = tab[(g * NSL + s) * 2 + 0];
            const unsigned int cn   = tab[(g * NSL + s) * 2 + 1];

            unsigned int i = t;
            for (; i + 256 < cn; i += 512) {
                const unsigned int w0 = buck[base + i];
                const unsigned int w1 = buck[base + i + 256];
                const int idx0 = (int)(w0 & 0xFFFFFu);
                const int idx1 = (int)(w1 & 0xFFFFFu);
                const int h0   = (int)(w0 >> 20);
                const int h1   = (int)(w1 >> 20);
                int a0, a1, a2, a3, a4, b0, b1, b2, b3, b4;
                load_row5(entries, idx0, a0, a1, a2, a3, a4);
                load_row5(entries, idx1, b0, b1, b2, b3, b4);
                atomicXor(&acc[h0 * 5 + 0], a0);
                atomicXor(&acc[h0 * 5 + 1], a1);
                atomicXor(&acc[h0 * 5 + 2], a2);
                atomicXor(&acc[h0 * 5 + 3], a3);
                atomicXor(&acc[h0 * 5 + 4], a4);
                atomicXor(&acc[h1 * 5 + 0], b0);
                atomicXor(&acc[h1 * 5 + 1], b1);
                atomicXor(&acc[h1 * 5 + 2], b2);
                atomicXor(&acc[h1 * 5 + 3], b3);
                atomicXor(&acc[h1 * 5 + 4], b4);
            }
            if (i < cn) {
                const unsigned int w = buck[base + i];
                const int idx = (int)(w & 0xFFFFFu);
                const int h   = (int)(w >> 20);
                int a0, a1, a2, a3, a4;
                load_row5(entries, idx, a0, a1, a2, a3, a4);
                atomicXor(&acc[h * 5 + 0], a0);
                atomicXor(&acc[h * 5 + 1], a1);
                atomicXor(&acc[h * 5 + 2], a2);
                atomicXor(&acc[h * 5 + 3], a3);
                atomicXor(&acc[h * 5 + 4], a4);
            }
        }
        __syncthreads();

        const long obase = (long)g * HPG * 5;
        const long omax  = (long)H * 5;
        for (int i = t; i < HPG * 5; i += 256) {
            const long o = obase + i;
            if (o < omax) {
                const int v = acc[i];
                if (v) atomicXor(&out[o], v);
            }
        }
        __syncthreads();
    }
}

// ---------------- Fallback (R1): direct gather, wave per hint ----------------
__global__ __launch_bounds__(256) void hint_xor_wave(
    const int* __restrict__ entries,
    const int* __restrict__ blocks,
    const int* __restrict__ offsets,
    const int* __restrict__ starts,
    const int* __restrict__ sizes,
    const int* __restrict__ bs_ptr,
    int* __restrict__ out,
    int H, int N)
{
    const int gtid = blockIdx.x * blockDim.x + threadIdx.x;
    const int hint = gtid >> 6;
    const int lane = gtid & 63;
    if (hint >= H) return;

    const int start = starts[hint];
    const int size  = sizes[hint];
    const int bs    = bs_ptr[0];

    int a0 = 0, a1 = 0, a2 = 0, a3 = 0, a4 = 0;
    for (int j = lane; j < size; j += 64) {
        int idx = clip_idx(blocks[start + j] * bs + offsets[start + j], N);
        const int* row = entries + (size_t)idx * 5;
        a0 ^= row[0]; a1 ^= row[1]; a2 ^= row[2]; a3 ^= row[3]; a4 ^= row[4];
    }
    #pragma unroll
    for (int m = 1; m < 64; m <<= 1) {
        a0 ^= __shfl_xor(a0, m);
        a1 ^= __shfl_xor(a1, m);
        a2 ^= __shfl_xor(a2, m);
        a3 ^= __shfl_xor(a3, m);
        a4 ^= __shfl_xor(a4, m);
    }
    if (lane == 0) {
        int* o = out + (size_t)hint * 5;
        o[0] = a0; o[1] = a1; o[2] = a2; o[3] = a3; o[4] = a4;
    }
}

extern "C" void kernel_launch(void* const* d_in, const int* in_sizes, int n_in,
                              void* d_out, int out_size, void* d_ws, size_t ws_size,
                              hipStream_t stream) {
    const int* entries = (const int*)d_in[0];
    const int* blocks  = (const int*)d_in[1];
    const int* offsets = (const int*)d_in[2];
    const int* starts  = (const int*)d_in[3];
    const int* sizes   = (const int*)d_in[4];
    const int* bs      = (const int*)d_in[5];
    int* out = (int*)d_out;

    const int H = in_sizes[3];
    const int T = in_sizes[1];
    const int N = in_sizes[0] / 5;

    const int NG  = (H + HPG - 1) / HPG;
    const int nSl = (N + 65535) >> 16;

    // ws layout: buck [T] u32 | tab [NG*NSL*2] u32
    const size_t buckOff   = 0;
    const size_t buckBytes = (size_t)T * 4;
    const size_t tabOff    = (buckOff + buckBytes + 63) & ~(size_t)63;
    const size_t need      = tabOff + (size_t)NG * NSL * 2 * 4 + 64;

    const bool ok = (N <= (1 << 20)) && (nSl <= NSL) && (ws_size >= need) &&
                    (H <= (1 << 27));

    if (ok) {
        unsigned int* buck = (unsigned int*)((char*)d_ws + buckOff);
        unsigned int* tab  = (unsigned int*)((char*)d_ws + tabOff);

        hipMemsetAsync(d_out, 0, (size_t)out_size * sizeof(int), stream);

        hipLaunchKernelGGL(bucket_kernel, dim3(NG), dim3(1024), 0, stream,
                           blocks, offsets, starts, bs, entries, out,
                           buck, tab, H, N, T);

        int gridB = 2048;
        if (gridB > NG * 8) gridB = NG * 8;
        const int gStride = (gridB >= 8) ? (gridB >> 3) : 1;
        const int gpb = (NG + gStride - 1) / gStride;

        hipLaunchKernelGGL(gather_kernel, dim3(gridB), dim3(256), 0, stream,
                           buck, tab, entries, out, H, NG, nSl, gpb);
    } else {
        const long total_threads = (long)H * 64;
        const int block = 256;
        const int grid = (int)((total_threads + block - 1) / block);
        hipLaunchKernelGGL(hint_xor_wave, dim3(grid), dim3(block), 0, stream,
                           entries, blocks, offsets, starts, sizes, bs, out, H, N);
    }
}

// Round 12
// 196.910 us; speedup vs baseline: 1.0308x; 1.0308x over previous
//
#include <hip/hip_runtime.h>

// Gather + ragged segment XOR reduction.
// History:
//  R1/R2: direct gather 142 us — L2-miss line-fill bound.
//  R4-R6: bucket-by-slice + XCD-pinned gather; R6 = bucket 30 + gather 61.4.
//  R7: padded 32B rows — confounded (4 MB/XCD >= L2, thrash). Reverted.
//  R8: ballot bucket — VALU-bound, 96 us. Reverted.
//  R9: u64 LDS atomicXor — memory-backed path on gfx950, NEVER. Reverted.
//  R10: 2x unrolled gather: 61.1, total 188.4 (best).
//  R11: int2 parity load — unprovable alignment -> compiler split to dwords +
//    selects; 74 us. Reverted. Gather pinned at ~61 us = ~10.5M random L2
//    line requests at ~7/cy/XCD (service-rate floor; alternatives rejected
//    by arithmetic in journal).
//  R12: single-pass bucket: fixed-CAP chunks (768 = +8 sigma), direct dword
//    scatter via LDS cursors (no stage/histogram/prefix), out-zeroing fused
//    (memset dispatch dropped). Gather = R10 with fixed-stride chunks.

#define HPG   128     // hints per group
#define NSL   16      // slices (idx>>16), N <= 2^20
#define CAP   768     // tokens per (group,slice) chunk; mean ~508, +8 sigma

__device__ __forceinline__ int clip_idx(int v, int N) {
    return min(max(v, 0), N - 1);
}

// ---------------- Kernel A: single-pass bucketize + out zeroing ----------------
__global__ __launch_bounds__(1024) void bucket_kernel(
    const int* __restrict__ blocks,
    const int* __restrict__ offsets,
    const int* __restrict__ starts,
    const int* __restrict__ bs_ptr,
    const int* __restrict__ entries,     // overflow path only
    int* __restrict__ out,               // zeroed here; overflow path XORs
    unsigned int* __restrict__ buck,     // [NG*NSL*CAP] u32: idx(20)|hint<<20
    unsigned int* __restrict__ tabCnt,   // [NG*NSL] u32
    int H, int N, int T)
{
    __shared__ int lstart[HPG + 1];
    __shared__ unsigned int lcur[NSL];

    const int g  = blockIdx.x;
    const int t  = threadIdx.x;
    const int h0 = g * HPG;
    const int h1 = min(H, h0 + HPG);
    const int nh = h1 - h0;
    const int bs = bs_ptr[0];

    if (t < nh) lstart[t] = starts[h0 + t];
    if (t == 0) lstart[nh] = (h1 < H) ? starts[h1] : T;
    if (t < NSL) lcur[t] = 0;

    // zero this group's slice of out (replaces the memset dispatch)
    {
        const long obase = (long)h0 * 5;
        const long ocnt  = (long)nh * 5;
        for (long i = t; i < ocnt; i += 1024) out[obase + i] = 0;
    }
    __syncthreads();

    const int tokBase = lstart[0];
    const int count   = lstart[nh] - tokBase;

    for (int i = t; i < count; i += 1024) {
        const int gpos = tokBase + i;
        const int idx  = clip_idx(blocks[gpos] * bs + offsets[gpos], N);
        int lo = 0, hi = nh - 1;                 // largest h: lstart[h] <= gpos
        while (lo < hi) {
            int m = (lo + hi + 1) >> 1;
            if (lstart[m] <= gpos) lo = m; else hi = m - 1;
        }
        const unsigned int s = (unsigned int)idx >> 16;
        const unsigned int r = atomicAdd(&lcur[s], 1u);
        if (r < CAP) {
            buck[((size_t)(g * NSL) + s) * CAP + r] =
                (unsigned int)idx | ((unsigned int)lo << 20);
        } else {
            // statistically never (CAP = +8 sigma); correctness fallback.
            const int* row = entries + (long)idx * 5;
            int* o5 = out + (long)(h0 + lo) * 5;
            atomicXor(&o5[0], row[0]); atomicXor(&o5[1], row[1]);
            atomicXor(&o5[2], row[2]); atomicXor(&o5[3], row[3]);
            atomicXor(&o5[4], row[4]);
        }
    }
    __syncthreads();

    if (t < NSL) tabCnt[g * NSL + t] = min(lcur[t], (unsigned int)CAP);
}

// ---------------- Kernel B: XCD-pinned gather + LDS accumulate (R10) ----------------
// Grid = 2048 (resident capacity) so blockIdx&7 -> XCD round-robin holds.
// Block (x,g) touches only slices {x, x+8} -> 2.62 MB entries, L2-resident.
__global__ __launch_bounds__(256) void gather_kernel(
    const unsigned int* __restrict__ buck,
    const unsigned int* __restrict__ tabCnt,
    const int* __restrict__ entries,
    int* __restrict__ out,
    int H, int NG, int nSl, int groupsPerBlock)
{
    __shared__ int acc[HPG * 5];

    const int B = blockIdx.x;
    const int x = B & 7;
    const int g0 = B >> 3;
    const int t = threadIdx.x;
    const int gStride = gridDim.x >> 3;

    for (int k = 0; k < groupsPerBlock; ++k) {
        const int g = g0 + k * gStride;
        if (g >= NG) break;

        for (int i = t; i < HPG * 5; i += 256) acc[i] = 0;
        __syncthreads();

        for (int s = x; s < nSl; s += 8) {
            const size_t base = ((size_t)(g * NSL) + s) * CAP;
            const unsigned int cn = tabCnt[g * NSL + s];

            unsigned int i = t;
            for (; i + 256 < cn; i += 512) {
                const unsigned int w0 = buck[base + i];
                const unsigned int w1 = buck[base + i + 256];
                const int idx0 = (int)(w0 & 0xFFFFFu);
                const int idx1 = (int)(w1 & 0xFFFFFu);
                const int h0   = (int)(w0 >> 20);
                const int h1   = (int)(w1 >> 20);
                const int* r0 = entries + (long)idx0 * 5;
                const int* r1 = entries + (long)idx1 * 5;
                const int a0 = r0[0], a1 = r0[1], a2 = r0[2], a3 = r0[3], a4 = r0[4];
                const int b0 = r1[0], b1 = r1[1], b2 = r1[2], b3 = r1[3], b4 = r1[4];
                atomicXor(&acc[h0 * 5 + 0], a0);
                atomicXor(&acc[h0 * 5 + 1], a1);
                atomicXor(&acc[h0 * 5 + 2], a2);
                atomicXor(&acc[h0 * 5 + 3], a3);
                atomicXor(&acc[h0 * 5 + 4], a4);
                atomicXor(&acc[h1 * 5 + 0], b0);
                atomicXor(&acc[h1 * 5 + 1], b1);
                atomicXor(&acc[h1 * 5 + 2], b2);
                atomicXor(&acc[h1 * 5 + 3], b3);
                atomicXor(&acc[h1 * 5 + 4], b4);
            }
            if (i < cn) {
                const unsigned int w = buck[base + i];
                const int idx = (int)(w & 0xFFFFFu);
                const int h   = (int)(w >> 20);
                const int* row = entries + (long)idx * 5;
                atomicXor(&acc[h * 5 + 0], row[0]);
                atomicXor(&acc[h * 5 + 1], row[1]);
                atomicXor(&acc[h * 5 + 2], row[2]);
                atomicXor(&acc[h * 5 + 3], row[3]);
                atomicXor(&acc[h * 5 + 4], row[4]);
            }
        }
        __syncthreads();

        const long obase = (long)g * HPG * 5;
        const long omax  = (long)H * 5;
        for (int i = t; i < HPG * 5; i += 256) {
            const long o = obase + i;
            if (o < omax) {
                const int v = acc[i];
                if (v) atomicXor(&out[o], v);
            }
        }
        __syncthreads();
    }
}

// ---------------- Fallback (R1): direct gather, wave per hint ----------------
__global__ __launch_bounds__(256) void hint_xor_wave(
    const int* __restrict__ entries,
    const int* __restrict__ blocks,
    const int* __restrict__ offsets,
    const int* __restrict__ starts,
    const int* __restrict__ sizes,
    const int* __restrict__ bs_ptr,
    int* __restrict__ out,
    int H, int N)
{
    const int gtid = blockIdx.x * blockDim.x + threadIdx.x;
    const int hint = gtid >> 6;
    const int lane = gtid & 63;
    if (hint >= H) return;

    const int start = starts[hint];
    const int size  = sizes[hint];
    const int bs    = bs_ptr[0];

    int a0 = 0, a1 = 0, a2 = 0, a3 = 0, a4 = 0;
    for (int j = lane; j < size; j += 64) {
        int idx = clip_idx(blocks[start + j] * bs + offsets[start + j], N);
        const int* row = entries + (size_t)idx * 5;
        a0 ^= row[0]; a1 ^= row[1]; a2 ^= row[2]; a3 ^= row[3]; a4 ^= row[4];
    }
    #pragma unroll
    for (int m = 1; m < 64; m <<= 1) {
        a0 ^= __shfl_xor(a0, m);
        a1 ^= __shfl_xor(a1, m);
        a2 ^= __shfl_xor(a2, m);
        a3 ^= __shfl_xor(a3, m);
        a4 ^= __shfl_xor(a4, m);
    }
    if (lane == 0) {
        int* o = out + (size_t)hint * 5;
        o[0] = a0; o[1] = a1; o[2] = a2; o[3] = a3; o[4] = a4;
    }
}

extern "C" void kernel_launch(void* const* d_in, const int* in_sizes, int n_in,
                              void* d_out, int out_size, void* d_ws, size_t ws_size,
                              hipStream_t stream) {
    const int* entries = (const int*)d_in[0];
    const int* blocks  = (const int*)d_in[1];
    const int* offsets = (const int*)d_in[2];
    const int* starts  = (const int*)d_in[3];
    const int* sizes   = (const int*)d_in[4];
    const int* bs      = (const int*)d_in[5];
    int* out = (int*)d_out;

    const int H = in_sizes[3];
    const int T = in_sizes[1];
    const int N = in_sizes[0] / 5;

    const int NG  = (H + HPG - 1) / HPG;
    const int nSl = (N + 65535) >> 16;

    // ws layout: buck [NG*NSL*CAP] u32 | tabCnt [NG*NSL] u32
    const size_t buckOff   = 0;
    const size_t buckBytes = (size_t)NG * NSL * CAP * 4;
    const size_t tabOff    = (buckOff + buckBytes + 63) & ~(size_t)63;
    const size_t need      = tabOff + (size_t)NG * NSL * 4 + 64;

    const bool ok = (N <= (1 << 20)) && (nSl <= NSL) && (ws_size >= need) &&
                    (H <= (1 << 27));

    if (ok) {
        unsigned int* buck   = (unsigned int*)((char*)d_ws + buckOff);
        unsigned int* tabCnt = (unsigned int*)((char*)d_ws + tabOff);

        hipLaunchKernelGGL(bucket_kernel, dim3(NG), dim3(1024), 0, stream,
                           blocks, offsets, starts, bs, entries, out,
                           buck, tabCnt, H, N, T);

        int gridB = 2048;
        if (gridB > NG * 8) gridB = NG * 8;
        const int gStride = (gridB >= 8) ? (gridB >> 3) : 1;
        const int gpb = (NG + gStride - 1) / gStride;

        hipLaunchKernelGGL(gather_kernel, dim3(gridB), dim3(256), 0, stream,
                           buck, tabCnt, entries, out, H, NG, nSl, gpb);
    } else {
        const long total_threads = (long)H * 64;
        const int block = 256;
        const int grid = (int)((total_threads + block - 1) / block);
        hipLaunchKernelGGL(hint_xor_wave, dim3(grid), dim3(block), 0, stream,
                           entries, blocks, offsets, starts, sizes, bs, out, H, N);
    }
}

// Round 13
// 189.879 us; speedup vs baseline: 1.0689x; 1.0370x over previous
//
#include <hip/hip_runtime.h>

// Gather + ragged segment XOR reduction — FINAL (R10 configuration, best: 188.4 us).
// History:
//  R1/R2: direct gather 142 us — L2-miss line-fill bound (table >> 4 MB/XCD L2).
//  R4-R6: bucket-by-slice + XCD-pinned gather; R6 = bucket ~30 + gather 61.4.
//  R7: padded 32B rows — confounded (slice pair 4 MB/XCD >= L2, thrash). Reverted.
//  R8: ballot-aggregated bucket — VALU-bound, 96 us. Reverted.
//  R9: u64 LDS atomicXor — memory-backed path on gfx950 (WRITE 20->100 MB). NEVER.
//  R10: 2x unrolled gather: 61.1, total 188.4 (BEST).
//  R11: parity int2 load — unprovable alignment, split+selects, 74 us. Reverted.
//  R12: single-pass bucket — lost phase separation/write merging, +8 us. Reverted.
// Ceiling accounting: ~96 us fixed harness overhead + ~1 memset + ~30 bucket
// (1.8x traffic floor; 4 restructures all regressed) + ~61 gather = ~10.5M
// random L2 line requests at ~7/cy/XCD service rate (floor by elimination:
// instr count x, load width x, ILP x, atomic width x).

#define HPG        128     // hints per group
#define NSL        16      // slices (idx>>16), N <= 2^20
#define STAGE_CAP  12288   // tokens staged in LDS; mean 8192, +10 sigma

__device__ __forceinline__ int clip_idx(int v, int N) {
    return min(max(v, 0), N - 1);
}

// ---------------- Kernel A: bucketize (one group per block) — R6 form ----------------
__global__ __launch_bounds__(1024) void bucket_kernel(
    const int* __restrict__ blocks,
    const int* __restrict__ offsets,
    const int* __restrict__ starts,
    const int* __restrict__ bs_ptr,
    const int* __restrict__ entries,     // overflow path only
    int* __restrict__ out,               // overflow path only
    unsigned int* __restrict__ buck,     // [T] u32: idx(20) | localHint(<<20)
    unsigned int* __restrict__ tab,      // [NG*NSL*2] {absBase, count}
    int H, int N, int T)
{
    __shared__ unsigned int stage[STAGE_CAP];
    __shared__ int lstart[HPG + 1];
    __shared__ unsigned int cnt[NSL], off[NSL], lcur[NSL];

    const int g  = blockIdx.x;
    const int t  = threadIdx.x;
    const int h0 = g * HPG;
    const int h1 = min(H, h0 + HPG);
    const int nh = h1 - h0;
    const int bs = bs_ptr[0];

    if (t < nh) lstart[t] = starts[h0 + t];
    if (t == 0) lstart[nh] = (h1 < H) ? starts[h1] : T;
    if (t < NSL) { cnt[t] = 0; lcur[t] = 0; }
    __syncthreads();

    const int tokBase = lstart[0];
    const int count   = lstart[nh] - tokBase;
    const int staged  = min(count, STAGE_CAP);

    // pass 1: idx + hint (binary search) -> LDS stage; per-slice histogram
    for (int i = t; i < staged; i += 1024) {
        const int gpos = tokBase + i;
        const int idx  = clip_idx(blocks[gpos] * bs + offsets[gpos], N);
        int lo = 0, hi = nh - 1;                 // largest h: lstart[h] <= gpos
        while (lo < hi) {
            int m = (lo + hi + 1) >> 1;
            if (lstart[m] <= gpos) lo = m; else hi = m - 1;
        }
        stage[i] = (unsigned int)idx | ((unsigned int)lo << 20);
        atomicAdd(&cnt[(unsigned int)idx >> 16], 1u);
    }
    __syncthreads();

    // exclusive prefix over 16 slice counts
    if (t == 0) {
        unsigned int run = 0;
        for (int s = 0; s < NSL; ++s) { off[s] = run; run += cnt[s]; }
    }
    __syncthreads();

    if (t < NSL) {
        tab[(g * NSL + t) * 2 + 0] = (unsigned int)tokBase + off[t];
        tab[(g * NSL + t) * 2 + 1] = cnt[t];
    }

    // pass 2: ordered scatter into the group's own CSR range
    for (int i = t; i < staged; i += 1024) {
        const unsigned int w = stage[i];
        const unsigned int s = (w >> 16) & (NSL - 1);
        const unsigned int r = atomicAdd(&lcur[s], 1u);
        buck[(unsigned int)tokBase + off[s] + r] = w;
    }

    // overflow remainder (count > STAGE_CAP): statistically never; correctness.
    for (int i = staged + t; i < count; i += 1024) {
        const int gpos = tokBase + i;
        const int idx  = clip_idx(blocks[gpos] * bs + offsets[gpos], N);
        int lo = 0, hi = nh - 1;
        while (lo < hi) {
            int m = (lo + hi + 1) >> 1;
            if (lstart[m] <= gpos) lo = m; else hi = m - 1;
        }
        const int* row = entries + (long)idx * 5;
        int* o5 = out + (long)(h0 + lo) * 5;
        atomicXor(&o5[0], row[0]); atomicXor(&o5[1], row[1]);
        atomicXor(&o5[2], row[2]); atomicXor(&o5[3], row[3]);
        atomicXor(&o5[4], row[4]);
    }
}

// ---------------- Kernel B: XCD-pinned gather + LDS accumulate ----------------
// Grid = 2048 (resident capacity) so blockIdx&7 -> XCD round-robin holds.
// Block (x,g) touches only slices {x, x+8} -> 2.62 MB entries, L2-resident.
// Token loop unrolled 2x — both rows' loads issued before the atomics.
__global__ __launch_bounds__(256) void gather_kernel(
    const unsigned int* __restrict__ buck,
    const unsigned int* __restrict__ tab,
    const int* __restrict__ entries,
    int* __restrict__ out,
    int H, int NG, int nSl, int groupsPerBlock)
{
    __shared__ int acc[HPG * 5];

    const int B = blockIdx.x;
    const int x = B & 7;
    const int g0 = B >> 3;
    const int t = threadIdx.x;
    const int gStride = gridDim.x >> 3;

    for (int k = 0; k < groupsPerBlock; ++k) {
        const int g = g0 + k * gStride;
        if (g >= NG) break;

        for (int i = t; i < HPG * 5; i += 256) acc[i] = 0;
        __syncthreads();

        for (int s = x; s < nSl; s += 8) {
            const unsigned int base = tab[(g * NSL + s) * 2 + 0];
            const unsigned int cn   = tab[(g * NSL + s) * 2 + 1];

            unsigned int i = t;
            for (; i + 256 < cn; i += 512) {
                const unsigned int w0 = buck[base + i];
                const unsigned int w1 = buck[base + i + 256];
                const int idx0 = (int)(w0 & 0xFFFFFu);
                const int idx1 = (int)(w1 & 0xFFFFFu);
                const int h0   = (int)(w0 >> 20);
                const int h1   = (int)(w1 >> 20);
                const int* r0 = entries + (long)idx0 * 5;
                const int* r1 = entries + (long)idx1 * 5;
                // issue all 10 loads before any atomic (ILP)
                const int a0 = r0[0], a1 = r0[1], a2 = r0[2], a3 = r0[3], a4 = r0[4];
                const int b0 = r1[0], b1 = r1[1], b2 = r1[2], b3 = r1[3], b4 = r1[4];
                atomicXor(&acc[h0 * 5 + 0], a0);
                atomicXor(&acc[h0 * 5 + 1], a1);
                atomicXor(&acc[h0 * 5 + 2], a2);
                atomicXor(&acc[h0 * 5 + 3], a3);
                atomicXor(&acc[h0 * 5 + 4], a4);
                atomicXor(&acc[h1 * 5 + 0], b0);
                atomicXor(&acc[h1 * 5 + 1], b1);
                atomicXor(&acc[h1 * 5 + 2], b2);
                atomicXor(&acc[h1 * 5 + 3], b3);
                atomicXor(&acc[h1 * 5 + 4], b4);
            }
            if (i < cn) {
                const unsigned int w = buck[base + i];
                const int idx = (int)(w & 0xFFFFFu);
                const int h   = (int)(w >> 20);
                const int* row = entries + (long)idx * 5;
                atomicXor(&acc[h * 5 + 0], row[0]);
                atomicXor(&acc[h * 5 + 1], row[1]);
                atomicXor(&acc[h * 5 + 2], row[2]);
                atomicXor(&acc[h * 5 + 3], row[3]);
                atomicXor(&acc[h * 5 + 4], row[4]);
            }
        }
        __syncthreads();

        const long obase = (long)g * HPG * 5;
        const long omax  = (long)H * 5;
        for (int i = t; i < HPG * 5; i += 256) {
            const long o = obase + i;
            if (o < omax) {
                const int v = acc[i];
                if (v) atomicXor(&out[o], v);
            }
        }
        __syncthreads();
    }
}

// ---------------- Fallback (R1): direct gather, wave per hint ----------------
__global__ __launch_bounds__(256) void hint_xor_wave(
    const int* __restrict__ entries,
    const int* __restrict__ blocks,
    const int* __restrict__ offsets,
    const int* __restrict__ starts,
    const int* __restrict__ sizes,
    const int* __restrict__ bs_ptr,
    int* __restrict__ out,
    int H, int N)
{
    const int gtid = blockIdx.x * blockDim.x + threadIdx.x;
    const int hint = gtid >> 6;
    const int lane = gtid & 63;
    if (hint >= H) return;

    const int start = starts[hint];
    const int size  = sizes[hint];
    const int bs    = bs_ptr[0];

    int a0 = 0, a1 = 0, a2 = 0, a3 = 0, a4 = 0;
    for (int j = lane; j < size; j += 64) {
        int idx = clip_idx(blocks[start + j] * bs + offsets[start + j], N);
        const int* row = entries + (size_t)idx * 5;
        a0 ^= row[0]; a1 ^= row[1]; a2 ^= row[2]; a3 ^= row[3]; a4 ^= row[4];
    }
    #pragma unroll
    for (int m = 1; m < 64; m <<= 1) {
        a0 ^= __shfl_xor(a0, m);
        a1 ^= __shfl_xor(a1, m);
        a2 ^= __shfl_xor(a2, m);
        a3 ^= __shfl_xor(a3, m);
        a4 ^= __shfl_xor(a4, m);
    }
    if (lane == 0) {
        int* o = out + (size_t)hint * 5;
        o[0] = a0; o[1] = a1; o[2] = a2; o[3] = a3; o[4] = a4;
    }
}

extern "C" void kernel_launch(void* const* d_in, const int* in_sizes, int n_in,
                              void* d_out, int out_size, void* d_ws, size_t ws_size,
                              hipStream_t stream) {
    const int* entries = (const int*)d_in[0];
    const int* blocks  = (const int*)d_in[1];
    const int* offsets = (const int*)d_in[2];
    const int* starts  = (const int*)d_in[3];
    const int* sizes   = (const int*)d_in[4];
    const int* bs      = (const int*)d_in[5];
    int* out = (int*)d_out;

    const int H = in_sizes[3];
    const int T = in_sizes[1];
    const int N = in_sizes[0] / 5;

    const int NG  = (H + HPG - 1) / HPG;
    const int nSl = (N + 65535) >> 16;

    // ws layout: buck [T] u32 | tab [NG*NSL*2] u32
    const size_t buckOff   = 0;
    const size_t buckBytes = (size_t)T * 4;
    const size_t tabOff    = (buckOff + buckBytes + 63) & ~(size_t)63;
    const size_t need      = tabOff + (size_t)NG * NSL * 2 * 4 + 64;

    const bool ok = (N <= (1 << 20)) && (nSl <= NSL) && (ws_size >= need) &&
                    (H <= (1 << 27));

    if (ok) {
        unsigned int* buck = (unsigned int*)((char*)d_ws + buckOff);
        unsigned int* tab  = (unsigned int*)((char*)d_ws + tabOff);

        hipMemsetAsync(d_out, 0, (size_t)out_size * sizeof(int), stream);

        hipLaunchKernelGGL(bucket_kernel, dim3(NG), dim3(1024), 0, stream,
                           blocks, offsets, starts, bs, entries, out,
                           buck, tab, H, N, T);

        int gridB = 2048;
        if (gridB > NG * 8) gridB = NG * 8;
        const int gStride = (gridB >= 8) ? (gridB >> 3) : 1;
        const int gpb = (NG + gStride - 1) / gStride;

        hipLaunchKernelGGL(gather_kernel, dim3(gridB), dim3(256), 0, stream,
                           buck, tab, entries, out, H, NG, nSl, gpb);
    } else {
        const long total_threads = (long)H * 64;
        const int block = 256;
        const int grid = (int)((total_threads + block - 1) / block);
        hipLaunchKernelGGL(hint_xor_wave, dim3(grid), dim3(block), 0, stream,
                           entries, blocks, offsets, starts, sizes, bs, out, H, N);
    }
}